// Round 12
// baseline (130.343 us; speedup 1.0000x reference)
//
#include <hip/hip_runtime.h>

#define IN_CH 96
#define OUT_CH 384
#define THREADS 384

typedef float f32x4 __attribute__((ext_vector_type(4)));
typedef float f32x2 __attribute__((ext_vector_type(2)));

// R8 winner (2ch/thread, 26-float pinned stash, nt stores, grid 768) with ONE
// structural change: the 3x-redundant per-lane x-window loads are replaced by
// ONE 16B load per lane + in-wave broadcast.
//
// Diagnosis: R8/R10/R11 plateau at ~107us regardless of MLP/prefetch -> a
// throughput bound. Load return traffic = 3 dwordx4 x 64 lanes = 3KB/instr
// ~= 36 B/cy/CU (window data is ~24x redundant across the 192 threads of a
// row), squeezing the 403MB store stream to 6 B/cy vs the 11 B/cy the fill
// kernels prove. Lane exchange moves the redundancy to the LDS-permute pipe,
// which runs in parallel with VMEM.
//
// Wave layout: lanes 8g..8g+7 all have the same joint (8 channel-pairs per
// joint, wave base p is 64-aligned so groups never straddle joints). Lane
// r=l&7 loads segment jc+min(r,2) (16B); the group's full 12-float window is
// then distributed to all 8 lanes via 12 __shfl broadcasts from lanes
// base+0/1/2. Edge clamping identical to R8 (jc = clamp(j-1,0,21); mask
// zeroes dead edge weights).
__global__ __launch_bounds__(THREADS, 5) void skel_linear_kernel(
    const float* __restrict__ x,
    const float* __restrict__ weight,
    const float* __restrict__ mask,
    const float* __restrict__ bias,
    float* __restrict__ out,
    int batch)
{
    const int t     = threadIdx.x;
    const int p     = t % 192;         // channel-pair index 0..191
    const int rl    = t / 192;         // 0..1
    const int chan  = p * 2;
    const int joint = p >> 3;
    const int jc    = (joint - 1 < 0) ? 0 : ((joint - 1 > 21) ? 21 : joint - 1);
    const int c0    = jc * 4;          // window base column

    const int r     = t & 7;                  // lane-in-group 0..7
    const int lbase = (t & 63) & ~7;          // group's first lane (wave-rel)
    const int segl  = jc + (r < 2 ? r : 2);   // segment THIS lane loads
    const int scol  = segl * 4;

    // Masked weights + bias, loaded once (26 floats: proven register-resident).
    float w[2][12];
    float b[2];
#pragma unroll
    for (int j = 0; j < 2; ++j) {
        const size_t row = (size_t)(chan + j) * IN_CH;
#pragma unroll
        for (int c = 0; c < 12; ++c)
            w[j][c] = weight[row + c0 + c] * mask[row + c0 + c];
        b[j] = bias[chan + j];
    }
#pragma unroll
    for (int j = 0; j < 2; ++j) {
#pragma unroll
        for (int c = 0; c < 12; ++c)
            asm volatile("" : "+v"(w[j][c]));
        asm volatile("" : "+v"(b[j]));
    }

    const int npairs = batch >> 1;     // 131072 row-pairs
    for (int q = blockIdx.x; q < npairs; q += gridDim.x) {
        const int row = q * 2 + rl;

        // ONE 16B load per lane (group lanes r=0,1,2 cover the whole window;
        // r>=3 duplicate segment jc+2 -> same cache line, coalesced away).
        const f32x4 v = *reinterpret_cast<const f32x4*>(
            x + (size_t)row * IN_CH + scol);

        // Broadcast the group's 3 segments to all 8 lanes (12 bpermutes).
        f32x4 xa, xb, xc;
#pragma unroll
        for (int c = 0; c < 4; ++c) {
            xa[c] = __shfl(v[c], lbase + 0);
            xb[c] = __shfl(v[c], lbase + 1);
            xc[c] = __shfl(v[c], lbase + 2);
        }

        f32x2 o2;
#pragma unroll
        for (int j = 0; j < 2; ++j) {
            float acc = b[j];
            acc = fmaf(w[j][0],  xa.x, acc);
            acc = fmaf(w[j][1],  xa.y, acc);
            acc = fmaf(w[j][2],  xa.z, acc);
            acc = fmaf(w[j][3],  xa.w, acc);
            acc = fmaf(w[j][4],  xb.x, acc);
            acc = fmaf(w[j][5],  xb.y, acc);
            acc = fmaf(w[j][6],  xb.z, acc);
            acc = fmaf(w[j][7],  xb.w, acc);
            acc = fmaf(w[j][8],  xc.x, acc);
            acc = fmaf(w[j][9],  xc.y, acc);
            acc = fmaf(w[j][10], xc.z, acc);
            acc = fmaf(w[j][11], xc.w, acc);
            o2[j] = acc;
        }

        __builtin_nontemporal_store(o2,
            reinterpret_cast<f32x2*>(out + (size_t)row * OUT_CH + chan));
    }
}

extern "C" void kernel_launch(void* const* d_in, const int* in_sizes, int n_in,
                              void* d_out, int out_size, void* d_ws, size_t ws_size,
                              hipStream_t stream) {
    const float* x      = (const float*)d_in[0];
    const float* weight = (const float*)d_in[1];
    const float* mask   = (const float*)d_in[2];
    const float* bias   = (const float*)d_in[3];
    float* out          = (float*)d_out;

    const int batch = in_sizes[0] / IN_CH;   // 262144
    const int grid  = 768;   // proven best (R4/R7: 768 > 1280)

    skel_linear_kernel<<<grid, THREADS, 0, stream>>>(x, weight, mask, bias, out, batch);
}

// Round 13
// 85.481 us; speedup vs baseline: 1.5248x; 1.5248x over previous
//
#include <hip/hip_runtime.h>

#define IN_CH 96
#define OUT_CH 384
#define THREADS 384
#define TILE 32    // rows staged per block-iteration (12 KB LDS)

typedef float f32x4 __attribute__((ext_vector_type(4)));
typedef float f32x2 __attribute__((ext_vector_type(2)));

// R13: LDS-staged x + broadcast ds_read, on the R8 winner's compute mapping.
// Diagnosis (R8..R12): L1 return-path throughput-bound — 3x dwordx4/lane/iter
// = 3KB/wave-iter (~48cy) of 21x-redundant window loads strangles the 403MB
// nt-store stream; MLP/prefetch/ordering all neutral; R12's shfl fix added
// serial bpermute latency (+21%). LDS staging loads each x byte from global
// exactly ONCE kernel-wide (~6cy/row L1) and serves the redundancy from the
// DS pipe, where same-address 8-lane ds_read_b128 broadcasts are free and
// pipelined (hidden by unroll-4 across rows, unlike R12's serial shfl chain).
// R1 tried this structure and got 127us with three now-fixed diseases:
// plain stores (proven 2x loss), unpinned weights (re-fetched per iter
// through the same L1), scalar ds_read_b32.
//
// Wave layout: all 64 lanes of a wave share rl -> same LDS row per sub-iter;
// the wave's ds_read addresses are <=8 distinct 16B quads on disjoint
// bank-quads -> conflict-free, no padding needed.
__global__ __launch_bounds__(THREADS, 5) void skel_linear_kernel(
    const float* __restrict__ x,
    const float* __restrict__ weight,
    const float* __restrict__ mask,
    const float* __restrict__ bias,
    float* __restrict__ out,
    int batch)
{
    const int t     = threadIdx.x;
    const int p     = t % 192;         // channel-pair index 0..191
    const int rl    = t / 192;         // 0..1 (uniform per wave)
    const int chan  = p * 2;
    const int joint = p >> 3;
    const int jc    = (joint - 1 < 0) ? 0 : ((joint - 1 > 21) ? 21 : joint - 1);
    const int c0    = jc * 4;          // contiguous 12-col window [c0, c0+12)

    // Masked weights + bias (26 floats: proven register-resident at this size).
    float w[2][12];
    float b[2];
#pragma unroll
    for (int j = 0; j < 2; ++j) {
        const size_t row = (size_t)(chan + j) * IN_CH;
#pragma unroll
        for (int c = 0; c < 12; ++c)
            w[j][c] = weight[row + c0 + c] * mask[row + c0 + c];
        b[j] = bias[chan + j];
    }
#pragma unroll
    for (int j = 0; j < 2; ++j) {
#pragma unroll
        for (int c = 0; c < 12; ++c)
            asm volatile("" : "+v"(w[j][c]));
        asm volatile("" : "+v"(b[j]));
    }

    __shared__ float xs[TILE * IN_CH];   // 32*96*4 = 12 KB

    const int ntiles = batch / TILE;     // 8192
    for (int tile = blockIdx.x; tile < ntiles; tile += gridDim.x) {
        // Stage 32 rows: 768 dwordx4, 2 per thread, perfectly coalesced.
        const f32x4* src = reinterpret_cast<const f32x4*>(
            x + (size_t)tile * (TILE * IN_CH));
        __syncthreads();                 // previous tile's readers done
        *reinterpret_cast<f32x4*>(&xs[4 * t])             = src[t];
        *reinterpret_cast<f32x4*>(&xs[4 * (t + THREADS)]) = src[t + THREADS];
        __syncthreads();                 // tile staged

        float* outb = out + (size_t)tile * (TILE * OUT_CH) + chan;
#pragma unroll 4
        for (int k = 0; k < TILE / 2; ++k) {
            const int rloc = 2 * k + rl;
            const float* xr = &xs[rloc * IN_CH + c0];
            const f32x4 xa = *reinterpret_cast<const f32x4*>(xr);
            const f32x4 xb = *reinterpret_cast<const f32x4*>(xr + 4);
            const f32x4 xc = *reinterpret_cast<const f32x4*>(xr + 8);

            f32x2 o2;
#pragma unroll
            for (int j = 0; j < 2; ++j) {
                float acc = b[j];
                acc = fmaf(w[j][0],  xa.x, acc);
                acc = fmaf(w[j][1],  xa.y, acc);
                acc = fmaf(w[j][2],  xa.z, acc);
                acc = fmaf(w[j][3],  xa.w, acc);
                acc = fmaf(w[j][4],  xb.x, acc);
                acc = fmaf(w[j][5],  xb.y, acc);
                acc = fmaf(w[j][6],  xb.z, acc);
                acc = fmaf(w[j][7],  xb.w, acc);
                acc = fmaf(w[j][8],  xc.x, acc);
                acc = fmaf(w[j][9],  xc.y, acc);
                acc = fmaf(w[j][10], xc.z, acc);
                acc = fmaf(w[j][11], xc.w, acc);
                o2[j] = acc;
            }

            __builtin_nontemporal_store(o2,
                reinterpret_cast<f32x2*>(outb + (size_t)rloc * OUT_CH));
        }
    }
}

extern "C" void kernel_launch(void* const* d_in, const int* in_sizes, int n_in,
                              void* d_out, int out_size, void* d_ws, size_t ws_size,
                              hipStream_t stream) {
    const float* x      = (const float*)d_in[0];
    const float* weight = (const float*)d_in[1];
    const float* mask   = (const float*)d_in[2];
    const float* bias   = (const float*)d_in[3];
    float* out          = (float*)d_out;

    const int batch = in_sizes[0] / IN_CH;   // 262144
    // 8192 tiles / 1024 blocks = exactly 8 tiles/block, 4 blocks/CU,
    // 24 waves/CU, 48 KB LDS/CU — no tail imbalance.
    const int grid = 1024;

    skel_linear_kernel<<<grid, THREADS, 0, stream>>>(x, weight, mask, bias, out, batch);
}

// Round 14
// 85.395 us; speedup vs baseline: 1.5264x; 1.0010x over previous
//
#include <hip/hip_runtime.h>

#define IN_CH 96
#define OUT_CH 384
#define THREADS 384
#define TILE 32    // rows staged per block-iteration (12 KB LDS)

typedef float f32x4 __attribute__((ext_vector_type(4)));
typedef float f32x2 __attribute__((ext_vector_type(2)));

// R13: LDS-staged x + broadcast ds_read, on the R8 winner's compute mapping.
// Diagnosis (R8..R12): L1 return-path throughput-bound — 3x dwordx4/lane/iter
// = 3KB/wave-iter (~48cy) of 21x-redundant window loads strangles the 403MB
// nt-store stream; MLP/prefetch/ordering all neutral; R12's shfl fix added
// serial bpermute latency (+21%). LDS staging loads each x byte from global
// exactly ONCE kernel-wide (~6cy/row L1) and serves the redundancy from the
// DS pipe, where same-address 8-lane ds_read_b128 broadcasts are free and
// pipelined (hidden by unroll-4 across rows, unlike R12's serial shfl chain).
// R1 tried this structure and got 127us with three now-fixed diseases:
// plain stores (proven 2x loss), unpinned weights (re-fetched per iter
// through the same L1), scalar ds_read_b32.
//
// Wave layout: all 64 lanes of a wave share rl -> same LDS row per sub-iter;
// the wave's ds_read addresses are <=8 distinct 16B quads on disjoint
// bank-quads -> conflict-free, no padding needed.
__global__ __launch_bounds__(THREADS, 5) void skel_linear_kernel(
    const float* __restrict__ x,
    const float* __restrict__ weight,
    const float* __restrict__ mask,
    const float* __restrict__ bias,
    float* __restrict__ out,
    int batch)
{
    const int t     = threadIdx.x;
    const int p     = t % 192;         // channel-pair index 0..191
    const int rl    = t / 192;         // 0..1 (uniform per wave)
    const int chan  = p * 2;
    const int joint = p >> 3;
    const int jc    = (joint - 1 < 0) ? 0 : ((joint - 1 > 21) ? 21 : joint - 1);
    const int c0    = jc * 4;          // contiguous 12-col window [c0, c0+12)

    // Masked weights + bias (26 floats: proven register-resident at this size).
    float w[2][12];
    float b[2];
#pragma unroll
    for (int j = 0; j < 2; ++j) {
        const size_t row = (size_t)(chan + j) * IN_CH;
#pragma unroll
        for (int c = 0; c < 12; ++c)
            w[j][c] = weight[row + c0 + c] * mask[row + c0 + c];
        b[j] = bias[chan + j];
    }
#pragma unroll
    for (int j = 0; j < 2; ++j) {
#pragma unroll
        for (int c = 0; c < 12; ++c)
            asm volatile("" : "+v"(w[j][c]));
        asm volatile("" : "+v"(b[j]));
    }

    __shared__ float xs[TILE * IN_CH];   // 32*96*4 = 12 KB

    const int ntiles = batch / TILE;     // 8192
    for (int tile = blockIdx.x; tile < ntiles; tile += gridDim.x) {
        // Stage 32 rows: 768 dwordx4, 2 per thread, perfectly coalesced.
        const f32x4* src = reinterpret_cast<const f32x4*>(
            x + (size_t)tile * (TILE * IN_CH));
        __syncthreads();                 // previous tile's readers done
        *reinterpret_cast<f32x4*>(&xs[4 * t])             = src[t];
        *reinterpret_cast<f32x4*>(&xs[4 * (t + THREADS)]) = src[t + THREADS];
        __syncthreads();                 // tile staged

        float* outb = out + (size_t)tile * (TILE * OUT_CH) + chan;
#pragma unroll 4
        for (int k = 0; k < TILE / 2; ++k) {
            const int rloc = 2 * k + rl;
            const float* xr = &xs[rloc * IN_CH + c0];
            const f32x4 xa = *reinterpret_cast<const f32x4*>(xr);
            const f32x4 xb = *reinterpret_cast<const f32x4*>(xr + 4);
            const f32x4 xc = *reinterpret_cast<const f32x4*>(xr + 8);

            f32x2 o2;
#pragma unroll
            for (int j = 0; j < 2; ++j) {
                float acc = b[j];
                acc = fmaf(w[j][0],  xa.x, acc);
                acc = fmaf(w[j][1],  xa.y, acc);
                acc = fmaf(w[j][2],  xa.z, acc);
                acc = fmaf(w[j][3],  xa.w, acc);
                acc = fmaf(w[j][4],  xb.x, acc);
                acc = fmaf(w[j][5],  xb.y, acc);
                acc = fmaf(w[j][6],  xb.z, acc);
                acc = fmaf(w[j][7],  xb.w, acc);
                acc = fmaf(w[j][8],  xc.x, acc);
                acc = fmaf(w[j][9],  xc.y, acc);
                acc = fmaf(w[j][10], xc.z, acc);
                acc = fmaf(w[j][11], xc.w, acc);
                o2[j] = acc;
            }

            __builtin_nontemporal_store(o2,
                reinterpret_cast<f32x2*>(outb + (size_t)rloc * OUT_CH));
        }
    }
}

extern "C" void kernel_launch(void* const* d_in, const int* in_sizes, int n_in,
                              void* d_out, int out_size, void* d_ws, size_t ws_size,
                              hipStream_t stream) {
    const float* x      = (const float*)d_in[0];
    const float* weight = (const float*)d_in[1];
    const float* mask   = (const float*)d_in[2];
    const float* bias   = (const float*)d_in[3];
    float* out          = (float*)d_out;

    const int batch = in_sizes[0] / IN_CH;   // 262144
    // 8192 tiles / 1024 blocks = exactly 8 tiles/block, 4 blocks/CU,
    // 24 waves/CU, 48 KB LDS/CU — no tail imbalance.
    const int grid = 1024;

    skel_linear_kernel<<<grid, THREADS, 0, stream>>>(x, weight, mask, bias, out, batch);
}

// Round 15
// 85.093 us; speedup vs baseline: 1.5318x; 1.0035x over previous
//
#include <hip/hip_runtime.h>

#define IN_CH 96
#define OUT_CH 384
#define THREADS 384
#define TILE 32    // rows staged per block-iteration (12 KB LDS)

typedef float f32x4 __attribute__((ext_vector_type(4)));
typedef float f32x2 __attribute__((ext_vector_type(2)));

// R13: LDS-staged x + broadcast ds_read, on the R8 winner's compute mapping.
// Diagnosis (R8..R12): L1 return-path throughput-bound — 3x dwordx4/lane/iter
// = 3KB/wave-iter (~48cy) of 21x-redundant window loads strangles the 403MB
// nt-store stream; MLP/prefetch/ordering all neutral; R12's shfl fix added
// serial bpermute latency (+21%). LDS staging loads each x byte from global
// exactly ONCE kernel-wide (~6cy/row L1) and serves the redundancy from the
// DS pipe, where same-address 8-lane ds_read_b128 broadcasts are free and
// pipelined (hidden by unroll-4 across rows, unlike R12's serial shfl chain).
// R1 tried this structure and got 127us with three now-fixed diseases:
// plain stores (proven 2x loss), unpinned weights (re-fetched per iter
// through the same L1), scalar ds_read_b32.
//
// Wave layout: all 64 lanes of a wave share rl -> same LDS row per sub-iter;
// the wave's ds_read addresses are <=8 distinct 16B quads on disjoint
// bank-quads -> conflict-free, no padding needed.
__global__ __launch_bounds__(THREADS, 5) void skel_linear_kernel(
    const float* __restrict__ x,
    const float* __restrict__ weight,
    const float* __restrict__ mask,
    const float* __restrict__ bias,
    float* __restrict__ out,
    int batch)
{
    const int t     = threadIdx.x;
    const int p     = t % 192;         // channel-pair index 0..191
    const int rl    = t / 192;         // 0..1 (uniform per wave)
    const int chan  = p * 2;
    const int joint = p >> 3;
    const int jc    = (joint - 1 < 0) ? 0 : ((joint - 1 > 21) ? 21 : joint - 1);
    const int c0    = jc * 4;          // contiguous 12-col window [c0, c0+12)

    // Masked weights + bias (26 floats: proven register-resident at this size).
    float w[2][12];
    float b[2];
#pragma unroll
    for (int j = 0; j < 2; ++j) {
        const size_t row = (size_t)(chan + j) * IN_CH;
#pragma unroll
        for (int c = 0; c < 12; ++c)
            w[j][c] = weight[row + c0 + c] * mask[row + c0 + c];
        b[j] = bias[chan + j];
    }
#pragma unroll
    for (int j = 0; j < 2; ++j) {
#pragma unroll
        for (int c = 0; c < 12; ++c)
            asm volatile("" : "+v"(w[j][c]));
        asm volatile("" : "+v"(b[j]));
    }

    __shared__ float xs[TILE * IN_CH];   // 32*96*4 = 12 KB

    const int ntiles = batch / TILE;     // 8192
    for (int tile = blockIdx.x; tile < ntiles; tile += gridDim.x) {
        // Stage 32 rows: 768 dwordx4, 2 per thread, perfectly coalesced.
        const f32x4* src = reinterpret_cast<const f32x4*>(
            x + (size_t)tile * (TILE * IN_CH));
        __syncthreads();                 // previous tile's readers done
        *reinterpret_cast<f32x4*>(&xs[4 * t])             = src[t];
        *reinterpret_cast<f32x4*>(&xs[4 * (t + THREADS)]) = src[t + THREADS];
        __syncthreads();                 // tile staged

        float* outb = out + (size_t)tile * (TILE * OUT_CH) + chan;
#pragma unroll 4
        for (int k = 0; k < TILE / 2; ++k) {
            const int rloc = 2 * k + rl;
            const float* xr = &xs[rloc * IN_CH + c0];
            const f32x4 xa = *reinterpret_cast<const f32x4*>(xr);
            const f32x4 xb = *reinterpret_cast<const f32x4*>(xr + 4);
            const f32x4 xc = *reinterpret_cast<const f32x4*>(xr + 8);

            f32x2 o2;
#pragma unroll
            for (int j = 0; j < 2; ++j) {
                float acc = b[j];
                acc = fmaf(w[j][0],  xa.x, acc);
                acc = fmaf(w[j][1],  xa.y, acc);
                acc = fmaf(w[j][2],  xa.z, acc);
                acc = fmaf(w[j][3],  xa.w, acc);
                acc = fmaf(w[j][4],  xb.x, acc);
                acc = fmaf(w[j][5],  xb.y, acc);
                acc = fmaf(w[j][6],  xb.z, acc);
                acc = fmaf(w[j][7],  xb.w, acc);
                acc = fmaf(w[j][8],  xc.x, acc);
                acc = fmaf(w[j][9],  xc.y, acc);
                acc = fmaf(w[j][10], xc.z, acc);
                acc = fmaf(w[j][11], xc.w, acc);
                o2[j] = acc;
            }

            __builtin_nontemporal_store(o2,
                reinterpret_cast<f32x2*>(outb + (size_t)rloc * OUT_CH));
        }
    }
}

extern "C" void kernel_launch(void* const* d_in, const int* in_sizes, int n_in,
                              void* d_out, int out_size, void* d_ws, size_t ws_size,
                              hipStream_t stream) {
    const float* x      = (const float*)d_in[0];
    const float* weight = (const float*)d_in[1];
    const float* mask   = (const float*)d_in[2];
    const float* bias   = (const float*)d_in[3];
    float* out          = (float*)d_out;

    const int batch = in_sizes[0] / IN_CH;   // 262144
    // 8192 tiles / 1024 blocks = exactly 8 tiles/block, 4 blocks/CU,
    // 24 waves/CU, 48 KB LDS/CU — no tail imbalance.
    const int grid = 1024;

    skel_linear_kernel<<<grid, THREADS, 0, stream>>>(x, weight, mask, bias, out, batch);
}